// Round 9
// baseline (124.158 us; speedup 1.0000x reference)
//
#include <hip/hip_runtime.h>

// DirichletLoss: ball-query (r=0.15, K=32) + 0.5*mean_i sum_k (f_i - f_nei)^2
// pos: [B,N,3] f32, f: [B,N] f32, out: scalar f32.
//
// R9: single fused kernel (+ one hipMemsetAsync for out). One workgroup per
// (batch, cell) of an 8^3 grid. Phase A: block scans all N=4096 points of
// its batch (L2-resident) and stages only points within r of the cell CUBE
// (Minkowski dilation — exact superset of possible neighbors of any query
// in the cell; ~232 avg at G=8), ballot-compacted into an LDS float4 buffer
// via a shared LDS cursor. Center-cell membership (cell_coord equality —
// each point claimed by exactly one block) recorded as queries (~8/cell).
// Phase B: one wave per query — scan staged candidates (valid-gated),
// ballot-compact in-ball (d2, fd2) into a per-wave LDS buffer, reload as 2
// register entries/lane, K-th-smallest d2 threshold via 12-iter ballot
// bisection (wave-uniform scalar control), sum fd2 below. Per-lane
// accumulate, single reduce, one atomicAdd per block.
//
// Why G=8 (R8 post-mortem): at G=6 the grid (1728 blocks, 6.75/CU vs
// 8-block/CU capacity) is fully resident at t=0 — no scheduler queue, so
// per-CU load imbalance IS the tail, and ~50% stall persists. G=8 gives
// 4096 blocks (16/CU, 2 rounds -> dynamic rebalancing), 4-chunk Phase B
// scans, and ~10.4 KB LDS. R7 lesson kept: minimal VGPR, no dual-query.
//
// Accuracy: tie-break by index dropped (measure-zero; R3-R8 absmax 0).
// 12-iter bisection residual r2*2^-12 ~ 5.5e-6 -> borderline-point error
// bound ~0.015 << 0.61 threshold.
//
// Capacity proofs (Binomial tails): dilated-cube candidates mean 232,
// sd 14.8 -> CAPC 384 = +10 sigma; in-ball M <= 128 (mean 58, sd 7.6,
// +9.3 sigma); queries/cell mean 8, sd 2.8 -> QMAX 32 = +8.5 sigma.

#define BQ_K 32
#define CAP 128            // per-wave in-ball buffer
#define WPB 4              // waves per block (block = 256)
#define G 8
#define NC (G * G * G)     // 512 cells
#define CAPC 384           // staged dilated-cube candidate cap
#define QMAX 32            // center-cell query cap
#define NPTS 4096          // compile-time N (reference fixes N=4096)

__device__ __forceinline__ int cell_coord(float x) {
    int c = (int)(x * (float)G);
    return c < 0 ? 0 : (c > G - 1 ? G - 1 : c);
}

// sum of fd2 over the K smallest d2 among the wave's 2-reg-per-lane set.
// M and the branch are wave-uniform. Sentinel entries have d2=1e30, y=0.
__device__ __forceinline__ float select_sum(float2 e0, float2 e1, int M,
                                            float r2) {
    if (M <= BQ_K) return e0.y + e1.y;     // all in-ball count; sentinels 0
    float lo = 0.0f, hi = r2 * 1.000001f;
    #pragma unroll
    for (int it = 0; it < 12; ++it) {
        const float mid = 0.5f * (lo + hi);
        const int cnt = __popcll(__ballot(e0.x < mid)) +
                        __popcll(__ballot(e1.x < mid));
        if (cnt >= BQ_K) hi = mid; else lo = mid;
    }
    float s = 0.0f;
    if (e0.x < hi) s = e0.y;
    if (e1.x < hi) s += e1.y;
    return s;
}

__global__ __launch_bounds__(256) void dl_fused(
    const float* __restrict__ pos, const float* __restrict__ f,
    float* __restrict__ out, float r2, float scale)
{
    __shared__ float4 s_cand[CAPC];
    __shared__ float2 s_sel[WPB][CAP];
    __shared__ int    s_q[QMAX];
    __shared__ int    s_ncand, s_nq;
    __shared__ float  s_wsum[WPB];

    const int bc = blockIdx.x;           // b*NC + c
    const int b  = bc / NC;
    const int c  = bc - b * NC;
    const int cx = c % G, cy = (c / G) % G, cz = c / (G * G);

    const int lane = threadIdx.x & 63;
    const int wave = threadIdx.x >> 6;
    const unsigned long long lmask = (1ULL << lane) - 1ULL;

    if (threadIdx.x == 0) { s_ncand = 0; s_nq = 0; }
    __syncthreads();

    const float* posb = pos + (size_t)b * NPTS * 3;
    const float* fb   = f   + (size_t)b * NPTS;

    // cell cube bounds (fp rounding harmless: prefilter has r slack, and
    // center-cell points have cube-distance ~0 regardless)
    const float lox = cx * (1.0f / G), hix = lox + (1.0f / G);
    const float loy = cy * (1.0f / G), hiy = loy + (1.0f / G);
    const float loz = cz * (1.0f / G), hiz = loz + (1.0f / G);

    // --- Phase A: stage points within r of the cell cube ---
    constexpr int per = NPTS / WPB;      // 1024 -> 16 chunks
    const int wbeg = wave * per;
    for (int j0 = 0; j0 < per; j0 += 64) {
        const int j = wbeg + j0 + lane;
        const float x  = posb[3 * j + 0];
        const float y  = posb[3 * j + 1];
        const float z  = posb[3 * j + 2];
        const float ddx = fmaxf(fmaxf(lox - x, x - hix), 0.0f);
        const float ddy = fmaxf(fmaxf(loy - y, y - hiy), 0.0f);
        const float ddz = fmaxf(fmaxf(loz - z, z - hiz), 0.0f);
        const float d2c = fmaf(ddx, ddx, fmaf(ddy, ddy, ddz * ddz));
        const bool in = (d2c <= r2);
        const unsigned long long m = __ballot(in);
        const int nh = __popcll(m);
        int base = 0;
        if (lane == 0 && nh) base = atomicAdd(&s_ncand, nh);
        base = __shfl(base, 0, 64);
        if (in) {
            const int off = base + __popcll(m & lmask);
            if (off < CAPC) {
                const float fj = fb[j];  // only staged points load f
                s_cand[off] = make_float4(x, y, z, fj);
                // exact center-cell membership -> query (claimed once)
                if (cell_coord(x) == cx && cell_coord(y) == cy &&
                    cell_coord(z) == cz) {
                    const int qs = atomicAdd(&s_nq, 1);
                    if (qs < QMAX) s_q[qs] = off;
                }
            }
        }
    }
    __syncthreads();

    const int ncand = s_ncand < CAPC ? s_ncand : CAPC;
    const int nq    = s_nq < QMAX ? s_nq : QMAX;
    const int ncB   = (ncand + 63) & ~63;

    float2* sel = s_sel[wave];
    float wsum = 0.0f;                   // per-lane accumulator

    // --- Phase B: one wave per query ---
    for (int qi = wave; qi < nq; qi += WPB) {
        const float4 qp = s_cand[s_q[qi]];   // wave-uniform LDS broadcast
        const float qx = qp.x, qy = qp.y, qz = qp.z, fi = qp.w;

        // scan staged candidates, compact in-ball (d2, fd2) into sel
        int cin = 0;
        for (int basej = 0; basej < ncB; basej += 64) {
            const float4 cd = s_cand[basej + lane];
            const bool valid = (basej + lane) < ncand;
            const float dx = cd.x - qx, dy = cd.y - qy, dz = cd.z - qz;
            const float d2 = fmaf(dx, dx, fmaf(dy, dy, dz * dz));
            const bool inb = valid && (d2 <= r2);
            const unsigned long long mm = __ballot(inb);
            const int off = cin + __popcll(mm & lmask);
            if (inb && off < CAP) {
                const float fd = fi - cd.w;
                sel[off] = make_float2(d2, fd * fd);
            }
            cin += __popcll(mm);
        }
        const int M = cin < CAP ? cin : CAP;

        const float2 e0 = (lane < M) ? sel[lane]
                                     : make_float2(1e30f, 0.0f);
        const float2 e1 = (64 + lane < M) ? sel[64 + lane]
                                          : make_float2(1e30f, 0.0f);
        wsum += select_sum(e0, e1, M, r2);
    }

    // --- single reduction at the end ---
    for (int o = 32; o > 0; o >>= 1) wsum += __shfl_down(wsum, o, 64);
    if (lane == 0) s_wsum[wave] = wsum;
    __syncthreads();
    if (threadIdx.x == 0) {
        const float bs = s_wsum[0] + s_wsum[1] + s_wsum[2] + s_wsum[3];
        atomicAdd(out, bs * scale);
    }
}

extern "C" void kernel_launch(void* const* d_in, const int* in_sizes, int n_in,
                              void* d_out, int out_size, void* d_ws, size_t ws_size,
                              hipStream_t stream) {
    const float* pos = (const float*)d_in[0];  // [B,N,3]
    const float* f   = (const float*)d_in[1];  // [B,N]
    float* out = (float*)d_out;

    const int B = in_sizes[1] / NPTS;  // 8
    const float r2 = 0.15f * 0.15f;
    const float scale = 0.5f / (float)((long long)B * NPTS);

    hipMemsetAsync(out, 0, sizeof(float), stream);
    dl_fused<<<B * NC, 256, 0, stream>>>(pos, f, out, r2, scale);
}

// Round 10
// 91.847 us; speedup vs baseline: 1.3518x; 1.3518x over previous
//
#include <hip/hip_runtime.h>

// DirichletLoss: ball-query (r=0.15, K=32) + 0.5*mean_i sum_k (f_i - f_nei)^2
// pos: [B,N,3] f32, f: [B,N] f32, out: scalar f32.
//
// R10: two kernels + two tiny memsets.
//  K1 dl_scatter: bin all B*N points into fixed-stride per-(batch,cell)
//     buckets (6^3 grid, cell 1/6 >= r; CMAX=64 slots, +10 sigma vs
//     Binomial mean 19 sd 4.3). d_ws is ~256 MiB (the harness poison fill
//     writes 268 MB), so bucket storage (1.78 MB) is free.
//  K2 dl_main: one workgroup per (batch, cell). Phase A: gather ONLY the 27
//     neighbor buckets (~512 reads, vs R8's full 4096-point scan — R9's
//     lesson: Phase A must scale with candidates, not N), prefilter by
//     distance-to-cell-cube <= r (Minkowski dilation, exact neighbor
//     superset, ~324 staged), ballot-compact into LDS float4 via shared
//     cursor. Bucket 13's points are exactly the center cell's -> they are
//     the query list. Phase B: one wave per query — scan staged candidates
//     (valid-gated), ballot-compact in-ball (d2, fd2) into per-wave LDS,
//     reload as 2 register entries/lane, K-th-smallest d2 threshold via
//     12-iter ballot bisection (wave-uniform), sum fd2 below. Per-lane
//     accumulate, single reduce, one atomicAdd per block.
//
// R7 lesson kept: minimal VGPR/LDS, no dual-query, no manual prefetch.
// Accuracy: tie-break by index dropped (measure-zero; R3-R9 absmax 0);
// 12-iter bisection residual r2*2^-12 ~ 5.5e-6 -> error ~0.015 << 0.61.
// Capacity proofs: CMAX 64 (+10 sigma); staged candidates mean 324 sd 17
// -> CAPC 512 (+11 sigma); in-ball M <= 128 (mean 58 sd 7.6, +9.3 sigma);
// queries/cell <= QMAX 64 (+10 sigma).

#define BQ_K 32
#define CAP 128            // per-wave in-ball buffer
#define WPB 4              // waves per block (block = 256)
#define G 6
#define NC (G * G * G)     // 216 cells
#define CMAX 64            // bucket slots per cell
#define CAPC 512           // staged dilated-cube candidate cap
#define QMAX 64            // center-cell query cap
#define NPTS 4096          // compile-time N (reference fixes N=4096)

__device__ __forceinline__ int cell_coord(float x) {
    int c = (int)(x * (float)G);
    return c < 0 ? 0 : (c > G - 1 ? G - 1 : c);
}

// sum of fd2 over the K smallest d2 among the wave's 2-reg-per-lane set.
// M and the branch are wave-uniform. Sentinel entries have d2=1e30, y=0.
__device__ __forceinline__ float select_sum(float2 e0, float2 e1, int M,
                                            float r2) {
    if (M <= BQ_K) return e0.y + e1.y;     // all in-ball count; sentinels 0
    float lo = 0.0f, hi = r2 * 1.000001f;
    #pragma unroll
    for (int it = 0; it < 12; ++it) {
        const float mid = 0.5f * (lo + hi);
        const int cnt = __popcll(__ballot(e0.x < mid)) +
                        __popcll(__ballot(e1.x < mid));
        if (cnt >= BQ_K) hi = mid; else lo = mid;
    }
    float s = 0.0f;
    if (e0.x < hi) s = e0.y;
    if (e1.x < hi) s += e1.y;
    return s;
}

__global__ void dl_scatter(const float* __restrict__ pos,
                           const float* __restrict__ f,
                           int* __restrict__ cnt, float4* __restrict__ buck,
                           int total) {
    const int t = blockIdx.x * blockDim.x + threadIdx.x;
    if (t >= total) return;
    const int b = t >> 12;               // t / NPTS
    const float x = pos[3 * (size_t)t + 0];
    const float y = pos[3 * (size_t)t + 1];
    const float z = pos[3 * (size_t)t + 2];
    const int c = (cell_coord(z) * G + cell_coord(y)) * G + cell_coord(x);
    const int cell = b * NC + c;
    const int slot = atomicAdd(&cnt[cell], 1);
    if (slot < CMAX)
        buck[(size_t)cell * CMAX + slot] = make_float4(x, y, z, f[t]);
}

__global__ __launch_bounds__(256) void dl_main(
    const int* __restrict__ cnt, const float4* __restrict__ buck,
    float* __restrict__ out, float r2, float scale)
{
    __shared__ float4 s_cand[CAPC];
    __shared__ float2 s_sel[WPB][CAP];
    __shared__ int    s_q[QMAX];
    __shared__ int    s_ncand, s_nq;
    __shared__ float  s_wsum[WPB];

    const int bc = blockIdx.x;           // b*NC + c
    const int b  = bc / NC;
    const int c  = bc - b * NC;
    const int cx = c % G, cy = (c / G) % G, cz = c / (G * G);

    const int lane = threadIdx.x & 63;
    const int wave = threadIdx.x >> 6;
    const unsigned long long lmask = (1ULL << lane) - 1ULL;

    if (threadIdx.x == 0) { s_ncand = 0; s_nq = 0; }
    __syncthreads();

    // cell cube bounds (fp rounding harmless: prefilter has r slack, and
    // center-bucket points pass at cube-distance 0)
    const float lox = cx * (1.0f / G), hix = lox + (1.0f / G);
    const float loy = cy * (1.0f / G), hiy = loy + (1.0f / G);
    const float loz = cz * (1.0f / G), hiz = loz + (1.0f / G);

    // --- Phase A: gather 27 neighbor buckets, Minkowski prefilter, stage ---
    for (int n = wave; n < 27; n += WPB) {
        const int nx = cx + (n % 3) - 1;
        const int ny = cy + ((n / 3) % 3) - 1;
        const int nz = cz + (n / 9) - 1;
        if ((unsigned)nx >= (unsigned)G || (unsigned)ny >= (unsigned)G ||
            (unsigned)nz >= (unsigned)G) continue;
        const int cell = b * NC + (nz * G + ny) * G + nx;
        int cc = cnt[cell];
        cc = cc < CMAX ? cc : CMAX;      // <= 64: one chunk per cell
        const bool have = lane < cc;
        float4 p = make_float4(1e30f, 1e30f, 1e30f, 0.0f);
        if (have) p = buck[(size_t)cell * CMAX + lane];
        const float ddx = fmaxf(fmaxf(lox - p.x, p.x - hix), 0.0f);
        const float ddy = fmaxf(fmaxf(loy - p.y, p.y - hiy), 0.0f);
        const float ddz = fmaxf(fmaxf(loz - p.z, p.z - hiz), 0.0f);
        const float d2c = fmaf(ddx, ddx, fmaf(ddy, ddy, ddz * ddz));
        const bool in = have && (d2c <= r2);
        const unsigned long long m = __ballot(in);
        const int nh = __popcll(m);
        int base = 0;
        if (lane == 0 && nh) base = atomicAdd(&s_ncand, nh);
        base = __shfl(base, 0, 64);
        if (in) {
            const int off = base + __popcll(m & lmask);
            if (off < CAPC) {
                s_cand[off] = p;
                if (n == 13) {           // center bucket -> query list
                    const int qs = atomicAdd(&s_nq, 1);
                    if (qs < QMAX) s_q[qs] = off;
                }
            }
        }
    }
    __syncthreads();

    const int ncand = s_ncand < CAPC ? s_ncand : CAPC;
    const int nq    = s_nq < QMAX ? s_nq : QMAX;
    const int ncB   = (ncand + 63) & ~63;

    float2* sel = s_sel[wave];
    float wsum = 0.0f;                   // per-lane accumulator

    // --- Phase B: one wave per query ---
    for (int qi = wave; qi < nq; qi += WPB) {
        const float4 qp = s_cand[s_q[qi]];   // wave-uniform LDS broadcast
        const float qx = qp.x, qy = qp.y, qz = qp.z, fi = qp.w;

        int cin = 0;
        for (int basej = 0; basej < ncB; basej += 64) {
            const float4 cd = s_cand[basej + lane];
            const bool valid = (basej + lane) < ncand;
            const float dx = cd.x - qx, dy = cd.y - qy, dz = cd.z - qz;
            const float d2 = fmaf(dx, dx, fmaf(dy, dy, dz * dz));
            const bool inb = valid && (d2 <= r2);
            const unsigned long long mm = __ballot(inb);
            const int off = cin + __popcll(mm & lmask);
            if (inb && off < CAP) {
                const float fd = fi - cd.w;
                sel[off] = make_float2(d2, fd * fd);
            }
            cin += __popcll(mm);
        }
        const int M = cin < CAP ? cin : CAP;

        const float2 e0 = (lane < M) ? sel[lane]
                                     : make_float2(1e30f, 0.0f);
        const float2 e1 = (64 + lane < M) ? sel[64 + lane]
                                          : make_float2(1e30f, 0.0f);
        wsum += select_sum(e0, e1, M, r2);
    }

    // --- single reduction at the end ---
    for (int o = 32; o > 0; o >>= 1) wsum += __shfl_down(wsum, o, 64);
    if (lane == 0) s_wsum[wave] = wsum;
    __syncthreads();
    if (threadIdx.x == 0) {
        const float bs = s_wsum[0] + s_wsum[1] + s_wsum[2] + s_wsum[3];
        atomicAdd(out, bs * scale);
    }
}

// ------------- single-kernel fallback (R8 structure) if ws too small -------
__global__ __launch_bounds__(256) void dl_fallback(
    const float* __restrict__ pos, const float* __restrict__ f,
    float* __restrict__ out, float r2, float scale)
{
    __shared__ float4 s_cand[CAPC];
    __shared__ float2 s_sel[WPB][CAP];
    __shared__ int    s_q[QMAX];
    __shared__ int    s_ncand, s_nq;
    __shared__ float  s_wsum[WPB];

    const int bc = blockIdx.x;
    const int b  = bc / NC;
    const int c  = bc - b * NC;
    const int cx = c % G, cy = (c / G) % G, cz = c / (G * G);
    const int lane = threadIdx.x & 63;
    const int wave = threadIdx.x >> 6;
    const unsigned long long lmask = (1ULL << lane) - 1ULL;

    if (threadIdx.x == 0) { s_ncand = 0; s_nq = 0; }
    __syncthreads();

    const float* posb = pos + (size_t)b * NPTS * 3;
    const float* fb   = f   + (size_t)b * NPTS;
    const float lox = cx * (1.0f / G), hix = lox + (1.0f / G);
    const float loy = cy * (1.0f / G), hiy = loy + (1.0f / G);
    const float loz = cz * (1.0f / G), hiz = loz + (1.0f / G);

    constexpr int per = NPTS / WPB;
    const int wbeg = wave * per;
    for (int j0 = 0; j0 < per; j0 += 64) {
        const int j = wbeg + j0 + lane;
        const float x  = posb[3 * j + 0];
        const float y  = posb[3 * j + 1];
        const float z  = posb[3 * j + 2];
        const float ddx = fmaxf(fmaxf(lox - x, x - hix), 0.0f);
        const float ddy = fmaxf(fmaxf(loy - y, y - hiy), 0.0f);
        const float ddz = fmaxf(fmaxf(loz - z, z - hiz), 0.0f);
        const float d2c = fmaf(ddx, ddx, fmaf(ddy, ddy, ddz * ddz));
        const bool in = (d2c <= r2);
        const unsigned long long m = __ballot(in);
        const int nh = __popcll(m);
        int base = 0;
        if (lane == 0 && nh) base = atomicAdd(&s_ncand, nh);
        base = __shfl(base, 0, 64);
        if (in) {
            const int off = base + __popcll(m & lmask);
            if (off < CAPC) {
                s_cand[off] = make_float4(x, y, z, fb[j]);
                if (cell_coord(x) == cx && cell_coord(y) == cy &&
                    cell_coord(z) == cz) {
                    const int qs = atomicAdd(&s_nq, 1);
                    if (qs < QMAX) s_q[qs] = off;
                }
            }
        }
    }
    __syncthreads();

    const int ncand = s_ncand < CAPC ? s_ncand : CAPC;
    const int nq    = s_nq < QMAX ? s_nq : QMAX;
    const int ncB   = (ncand + 63) & ~63;
    float2* sel = s_sel[wave];
    float wsum = 0.0f;

    for (int qi = wave; qi < nq; qi += WPB) {
        const float4 qp = s_cand[s_q[qi]];
        const float qx = qp.x, qy = qp.y, qz = qp.z, fi = qp.w;
        int cin = 0;
        for (int basej = 0; basej < ncB; basej += 64) {
            const float4 cd = s_cand[basej + lane];
            const bool valid = (basej + lane) < ncand;
            const float dx = cd.x - qx, dy = cd.y - qy, dz = cd.z - qz;
            const float d2 = fmaf(dx, dx, fmaf(dy, dy, dz * dz));
            const bool inb = valid && (d2 <= r2);
            const unsigned long long mm = __ballot(inb);
            const int off = cin + __popcll(mm & lmask);
            if (inb && off < CAP) {
                const float fd = fi - cd.w;
                sel[off] = make_float2(d2, fd * fd);
            }
            cin += __popcll(mm);
        }
        const int M = cin < CAP ? cin : CAP;
        const float2 e0 = (lane < M) ? sel[lane] : make_float2(1e30f, 0.0f);
        const float2 e1 = (64 + lane < M) ? sel[64 + lane]
                                          : make_float2(1e30f, 0.0f);
        wsum += select_sum(e0, e1, M, r2);
    }

    for (int o = 32; o > 0; o >>= 1) wsum += __shfl_down(wsum, o, 64);
    if (lane == 0) s_wsum[wave] = wsum;
    __syncthreads();
    if (threadIdx.x == 0) {
        const float bs = s_wsum[0] + s_wsum[1] + s_wsum[2] + s_wsum[3];
        atomicAdd(out, bs * scale);
    }
}

extern "C" void kernel_launch(void* const* d_in, const int* in_sizes, int n_in,
                              void* d_out, int out_size, void* d_ws, size_t ws_size,
                              hipStream_t stream) {
    const float* pos = (const float*)d_in[0];  // [B,N,3]
    const float* f   = (const float*)d_in[1];  // [B,N]
    float* out = (float*)d_out;

    const int B = in_sizes[1] / NPTS;  // 8
    const int total = B * NPTS;
    const float r2 = 0.15f * 0.15f;
    const float scale = 0.5f / (float)total;

    hipMemsetAsync(out, 0, sizeof(float), stream);

    const size_t cnt_bytes  = (size_t)B * NC * sizeof(int);          // 6912
    const size_t buck_bytes = (size_t)B * NC * CMAX * sizeof(float4);
    if (ws_size < cnt_bytes + buck_bytes) {
        dl_fallback<<<B * NC, 256, 0, stream>>>(pos, f, out, r2, scale);
        return;
    }

    int*    cnt  = (int*)d_ws;
    float4* buck = (float4*)((char*)d_ws + cnt_bytes);

    hipMemsetAsync(cnt, 0, cnt_bytes, stream);
    dl_scatter<<<(total + 255) / 256, 256, 0, stream>>>(pos, f, cnt, buck, total);
    dl_main   <<<B * NC, 256, 0, stream>>>(cnt, buck, out, r2, scale);
}